// Round 4
// baseline (205.509 us; speedup 1.0000x reference)
//
#include <hip/hip_runtime.h>
#include <hip/hip_bf16.h>

// B=16, S=2048, D=128 causal attention, pre-scale threshold:
//   A = Q@T^T; A = (A>0.3 ? A : 0); causal -2^32; /sqrt(128); softmax; @V
// fp32 in/out, bf16 MFMA internal. Fixed-max softmax (m=0; post-threshold
// logits in [0,~9]) => partial (oacc, sum-l) accumulators are ADDITIVE.
//
// V5: 32x32x16 MFMA, swapped QK^T (S^T = T.Q^T) so each lane owns one q-row's
// P-values => softmax fully in-register (no P LDS round-trip, no shfl trees).
// PV A-frag built by plain bf16 casts; the key permutation of the A-frag is
// matched on the B side by reading V at the same permuted key offsets
// (2x ds_read_b64) -- MFMA only needs A/B key-slot consistency.
// Each wave covers 32 q-rows (BQ=128/block): the 32KB/tile LDS read amortizes
// over 2x the work vs V4 (~3x lower LDS cycles/work, 2x fewer barriers).
// Staging: global_load_lds 16B DMA, double-buffered, counted vmcnt(8) (V4).
// Grid 512 = (b, pair i of q-tiles (i,15-i), chunk 0..3 of the 34-tile pair
// enumeration [0,9,17,26,34)). Light q-tile: 1-2 contributors; heavy: 3-4
// with chunk3 as finalizer (spin on done counter; all 512 blocks co-resident
// at 2/CU so spin is safe; counters zeroed by prep each launch).
// Partials in bf16 (error ~2e-4 after /l): ws ~29.5MB.

#define S_LEN 2048
#define D_DIM 128
#define THRESH 0.3f
#define SCALE 0.08838834764831845f   // 1/sqrt(128)

typedef __bf16 bf16x8 __attribute__((ext_vector_type(8)));
typedef float f32x4 __attribute__((ext_vector_type(4)));
typedef float f32x16 __attribute__((ext_vector_type(16)));
typedef unsigned long long u64;
typedef unsigned long long u64x2 __attribute__((ext_vector_type(2)));

#define GLD16(g, l)                                                         \
    __builtin_amdgcn_global_load_lds(                                       \
        (const __attribute__((address_space(1))) unsigned int*)(g),         \
        (__attribute__((address_space(3))) unsigned int*)(l), 16, 0, 0)

// ---- prep: Tb bf16 downcast; Vt[b][d][s] bf16 transpose; zero done ctrs ----
__global__ void prep_kernel(const float* __restrict__ V, const float* __restrict__ T,
                            __bf16* __restrict__ Vt, __bf16* __restrict__ Tb,
                            int* __restrict__ done) {
    __shared__ float tile[64][65];
    int bid = blockIdx.x;                      // 1024 blocks
    int tid = threadIdx.x;                     // 256 threads
    if (bid == 0) done[tid] = 0;
    int b  = bid >> 6;
    int t2 = bid & 63;

    {   // T downcast: rows [t2*32, t2*32+32) of batch b; 16 f32 per thread
        int flat = tid * 16;
        int r = flat >> 7, cc = flat & 127;
        const float* p = T + ((size_t)b * S_LEN + t2 * 32 + r) * D_DIM + cc;
        __bf16* q = Tb + ((size_t)b * S_LEN + t2 * 32 + r) * D_DIM + cc;
        bf16x8 w0, w1;
        f32x4 a0 = *(const f32x4*)p,       a1 = *(const f32x4*)(p + 4);
        f32x4 a2 = *(const f32x4*)(p + 8), a3 = *(const f32x4*)(p + 12);
        #pragma unroll
        for (int j = 0; j < 4; ++j) {
            w0[j] = (__bf16)a0[j]; w0[4 + j] = (__bf16)a1[j];
            w1[j] = (__bf16)a2[j]; w1[4 + j] = (__bf16)a3[j];
        }
        *(bf16x8*)q = w0;
        *(bf16x8*)(q + 8) = w1;
    }

    int s0 = (t2 >> 1) * 64;
    int d0 = (t2 & 1) * 64;
    #pragma unroll
    for (int it = 0; it < 2; ++it) {
        int row = it * 32 + (tid >> 3);
        int c   = (tid & 7) * 8;
        const float* p = V + ((size_t)b * S_LEN + s0 + row) * D_DIM + d0 + c;
        *(f32x4*)(&tile[row][c])     = *(const f32x4*)p;
        *(f32x4*)(&tile[row][c + 4]) = *(const f32x4*)(p + 4);
    }
    __syncthreads();
    #pragma unroll
    for (int it = 0; it < 2; ++it) {
        int dr = it * 32 + (tid >> 3);
        int c  = (tid & 7) * 8;
        bf16x8 w;
        #pragma unroll
        for (int j = 0; j < 8; ++j) w[j] = (__bf16)tile[c + j][dr];
        *(bf16x8*)(Vt + ((size_t)b * D_DIM + d0 + dr) * S_LEN + s0 + c) = w;
    }
}

// ---------------- Flash attention, causal + threshold, fixed-max ----------------
// 256 threads = 4 waves, each wave owns 32 q-rows (BQ=128). LDS 64KB (2/CU):
//   [    0, 32768)  Tt dbuf: 2 x (64 rows x 256B), XOR-swizzled via DMA source
//   [32768, 65536)  Vl dbuf: 2 x (128 rows x 128B), XOR-swizzled via DMA source
__global__ __launch_bounds__(256, 2)
void fa_kernel(const float* __restrict__ Q, const __bf16* __restrict__ Tb,
               const __bf16* __restrict__ Vt, float* __restrict__ O,
               __bf16* __restrict__ pO, float* __restrict__ pL,
               int* __restrict__ done) {
    __shared__ __align__(16) unsigned char smem[65536];

    const int bid = blockIdx.x;          // 512 = b(4b) | pair(3b) | chunk(2b)
    const int b   = bid & 15;
    const int pi  = (bid >> 4) & 7;      // pair: q-tiles (pi, 15-pi), 128 rows each
    const int c   = bid >> 7;            // chunk 0..3 of [0,9,17,26,34)
    const int L2  = 2 * pi + 2;          // light k-tile count
    const int pr  = b * 8 + pi;          // pair id 0..127

    const int tid  = threadIdx.x;
    const int lane = tid & 63;
    const int wv   = tid >> 6;
    const int l31  = lane & 31;
    const int hi   = lane >> 5;

    const __bf16* TbB = Tb + (size_t)b * (S_LEN * D_DIM);
    const __bf16* VtB = Vt + (size_t)b * (D_DIM * S_LEN);

    // per-thread pre-swizzled global source offsets for the 4+4 DMA issues
    int toff[4], voff[4];
    #pragma unroll
    for (int i = 0; i < 4; ++i) {
        int trw = wv * 16 + i * 4 + (lane >> 4);
        toff[i] = trw * 128 + (((lane & 15) ^ (trw & 7)) << 3);
        int drw = wv * 32 + i * 8 + (lane >> 3);
        voff[i] = drw * 2048 + (((lane & 7) ^ (drw & 7)) << 3);
    }

    auto issueTile = [&](int k0, int buf) {
        const __bf16* ts = TbB + (size_t)k0 * D_DIM;
        const __bf16* vs = VtB + k0;
        unsigned char* lt = smem + buf * 16384 + wv * 4096;
        unsigned char* lv = smem + 32768 + buf * 16384 + wv * 4096;
        #pragma unroll
        for (int i = 0; i < 4; ++i) GLD16(ts + toff[i], lt + i * 1024);
        #pragma unroll
        for (int i = 0; i < 4; ++i) GLD16(vs + voff[i], lv + i * 1024);
    };

    // Q B-frags: lane holds Q[q = l31 (+wave offset)][d = 16kk + 8hi + j]
    bf16x8 qf[8];
    auto loadQ = [&](int jq) {
        const float* qptr = Q + ((size_t)b * S_LEN + jq * 128 + wv * 32 + l31) * D_DIM + hi * 8;
        #pragma unroll
        for (int kk = 0; kk < 8; ++kk) {
            f32x4 a = *(const f32x4*)(qptr + kk * 16);
            f32x4 d = *(const f32x4*)(qptr + kk * 16 + 4);
            #pragma unroll
            for (int j = 0; j < 4; ++j) { qf[kk][j] = (__bf16)a[j]; qf[kk][4 + j] = (__bf16)d[j]; }
        }
    };

    f32x16 oacc[4];       // D[q = (g&3)+8*(g>>2)+4*hi][d = 32dt + l31]
    float  lsum;          // per-lane: q-row l31, keys of this lane's hi-half

    auto computeTile = [&](int buf, int jq, int kt) {
        unsigned char* Tt = smem + buf * 16384;
        unsigned char* Vl = smem + 32768 + buf * 16384;
        f32x16 sacc0 = {}, sacc1 = {};
        __builtin_amdgcn_s_setprio(1);
        #pragma unroll
        for (int kk = 0; kk < 8; ++kk) {
            int r0 = l31;
            bf16x8 tf0 = *(const bf16x8*)(Tt + r0 * 256 + ((kk * 32 + hi * 16) ^ ((r0 & 7) << 4)));
            sacc0 = __builtin_amdgcn_mfma_f32_32x32x16_bf16(tf0, qf[kk], sacc0, 0, 0, 0);
            int r1 = 32 + l31;
            bf16x8 tf1 = *(const bf16x8*)(Tt + r1 * 256 + ((kk * 32 + hi * 16) ^ ((r1 & 7) << 4)));
            sacc1 = __builtin_amdgcn_mfma_f32_32x32x16_bf16(tf1, qf[kk], sacc1, 0, 0, 0);
        }
        __builtin_amdgcn_s_setprio(0);

        // S^T: col = q = l31, row = key = 32t + (g&3)+8*(g>>2)+4*hi
        const int qin = wv * 32 + l31;
        const int dK  = 128 * jq - 64 * kt;     // >=64 for non-diag tiles
        float p[2][16];
        #pragma unroll
        for (int g = 0; g < 16; ++g) {
            float s0 = sacc0[g], s1 = sacc1[g];
            float e0 = __expf(s0 * SCALE), e1 = __expf(s1 * SCALE);
            p[0][g] = (s0 > THRESH) ? e0 : 1.0f;
            p[1][g] = (s1 > THRESH) ? e1 : 1.0f;
        }
        if (dK < 64) {                           // causal mask (diag tiles only)
            #pragma unroll
            for (int t = 0; t < 2; ++t)
                #pragma unroll
                for (int g = 0; g < 16; ++g) {
                    int key = t * 32 + (g & 3) + 8 * (g >> 2) + 4 * hi;
                    if (key - qin > dK) p[t][g] = 0.0f;
                }
        }
        float ls = 0.f;
        #pragma unroll
        for (int g = 0; g < 16; ++g) ls += (p[0][g] + p[1][g]);
        lsum += ls;

        // PV A-frags in-register: pka[ks][j] = P[q][key = 16ks + 8*(j>=4) + 4hi + (j&3)]
        bf16x8 pka[4];
        #pragma unroll
        for (int ks = 0; ks < 4; ++ks)
            #pragma unroll
            for (int j = 0; j < 8; ++j)
                pka[ks][j] = (__bf16)p[ks >> 1][8 * (ks & 1) + j];

        __builtin_amdgcn_s_setprio(1);
        #pragma unroll
        for (int ks = 0; ks < 4; ++ks) {
            #pragma unroll
            for (int dt = 0; dt < 4; ++dt) {
                int d = dt * 32 + l31;
                // B-frag at the SAME permuted key slots as pka (consistency is
                // all MFMA needs): keys 16ks+4hi+{0..3} and 16ks+8+4hi+{0..3}
                u64x2 vv;
                vv[0] = *(const u64*)(Vl + d * 128 + ((((2 * ks)     ^ (d & 7)) << 4) + 8 * hi));
                vv[1] = *(const u64*)(Vl + d * 128 + ((((2 * ks + 1) ^ (d & 7)) << 4) + 8 * hi));
                bf16x8 vf = __builtin_bit_cast(bf16x8, vv);
                oacc[dt] = __builtin_amdgcn_mfma_f32_32x32x16_bf16(pka[ks], vf, oacc[dt], 0, 0, 0);
            }
        }
        __builtin_amdgcn_s_setprio(0);
    };

    auto runSeg = [&](int jq, int k0t, int nt) {
        loadQ(jq);
        f32x16 z = {};
        #pragma unroll
        for (int dt = 0; dt < 4; ++dt) oacc[dt] = z;
        lsum = 0.f;
        issueTile(k0t * 64, 0);
        for (int s = 0; s < nt; ++s) {
            if (s + 1 < nt) {
                issueTile((k0t + s + 1) * 64, (s + 1) & 1);
                asm volatile("s_waitcnt vmcnt(8)" ::: "memory");  // tile s done; s+1 in flight
            } else {
                asm volatile("s_waitcnt vmcnt(0)" ::: "memory");
            }
            __builtin_amdgcn_s_barrier();
            computeTile(s & 1, jq, k0t + s);
            __builtin_amdgcn_s_barrier();
        }
    };

    auto reduceL = [&]() -> float { return lsum + __shfl_xor(lsum, 32); };

    auto storeOfinal = [&](int jq, float l_all) {
        float linv = 1.0f / l_all;                // lane's own q = l31
        float* optr = O + ((size_t)b * S_LEN + jq * 128 + wv * 32) * D_DIM;
        #pragma unroll
        for (int g = 0; g < 16; ++g) {
            int ql = (g & 3) + 8 * (g >> 2) + 4 * hi;
            float iv = __shfl(linv, ql);
            #pragma unroll
            for (int dt = 0; dt < 4; ++dt)
                optr[ql * D_DIM + dt * 32 + l31] = oacc[dt][g] * iv;
        }
    };

    auto storePartial = [&](int slot, float l_all, int* dcnt) {
        __bf16* po = pO + (size_t)(pr * 3 + slot) * (128 * 128);
        float*  pl = pL + (size_t)(pr * 3 + slot) * 128;
        #pragma unroll
        for (int g = 0; g < 16; ++g) {
            int row = wv * 32 + (g & 3) + 8 * (g >> 2) + 4 * hi;
            #pragma unroll
            for (int dt = 0; dt < 4; ++dt)
                po[row * 128 + dt * 32 + l31] = (__bf16)oacc[dt][g];
        }
        if (lane < 32) pl[wv * 32 + lane] = l_all;
        __threadfence();
        __syncthreads();
        if (tid == 0)
            __hip_atomic_fetch_add(dcnt, 1, __ATOMIC_RELEASE, __HIP_MEMORY_SCOPE_AGENT);
    };

    auto addPartial = [&](int slot, float* l_all) {
        const __bf16* po = pO + (size_t)(pr * 3 + slot) * (128 * 128);
        const float*  pl = pL + (size_t)(pr * 3 + slot) * 128;
        #pragma unroll
        for (int g = 0; g < 16; ++g) {
            int row = wv * 32 + (g & 3) + 8 * (g >> 2) + 4 * hi;
            #pragma unroll
            for (int dt = 0; dt < 4; ++dt)
                oacc[dt][g] += (float)po[row * 128 + dt * 32 + l31];
        }
        *l_all += pl[wv * 32 + l31];
    };

    auto spinFor = [&](int* dcnt, int need) {
        if (tid == 0) {
            while (__hip_atomic_load(dcnt, __ATOMIC_ACQUIRE, __HIP_MEMORY_SCOPE_AGENT) < need)
                __builtin_amdgcn_s_sleep(8);
        }
        __syncthreads();
        __threadfence();
    };

    // ---- chunk schedule ----
    if (c == 0) {
        if (pi <= 3) {
            runSeg(pi, 0, L2);                       // light, complete
            storeOfinal(pi, reduceL());
            runSeg(15 - pi, 0, 9 - L2);              // heavy prefix
            float lh = reduceL();
            storePartial(0, lh, &done[128 + pr]);
        } else {
            runSeg(pi, 0, 9);                        // light part 1
            float la = reduceL();
            storePartial(0, la, &done[pr]);
        }
    } else if (c == 1) {
        if (pi <= 3) {
            runSeg(15 - pi, 9 - L2, 8);
            float lh = reduceL();
            storePartial(1, lh, &done[128 + pr]);
        } else {
            runSeg(15 - pi, 0, 17 - L2);             // heavy first (lets c0 finish)
            float lh = reduceL();
            storePartial(1, lh, &done[128 + pr]);
            runSeg(pi, 9, L2 - 9);                   // light part 2 + finalize
            float la = reduceL();
            spinFor(&done[pr], 1);
            addPartial(0, &la);
            storeOfinal(pi, la);
        }
    } else if (c == 2) {
        runSeg(15 - pi, 17 - L2, 9);
        float lh = reduceL();
        storePartial(2, lh, &done[128 + pr]);
    } else {
        runSeg(15 - pi, 26 - L2, 8);                 // heavy tail incl. diag tiles
        float lh = reduceL();
        int s0 = (pi <= 3) ? 0 : 1;
        spinFor(&done[128 + pr], 3 - s0);
        for (int s = s0; s < 3; ++s) addPartial(s, &lh);
        storeOfinal(15 - pi, lh);
    }
}

extern "C" void kernel_launch(void* const* d_in, const int* in_sizes, int n_in,
                              void* d_out, int out_size, void* d_ws, size_t ws_size,
                              hipStream_t stream) {
    const float* Q = (const float*)d_in[0];
    const float* T = (const float*)d_in[1];
    const float* V = (const float*)d_in[2];
    float* O = (float*)d_out;

    // ws: Vt 8MB | Tb 8MB | pO 12MB bf16 | pL 192KB | done 1KB  (~29.6MB)
    unsigned char* ws = (unsigned char*)d_ws;
    __bf16* Vt = (__bf16*)ws;
    __bf16* Tb = (__bf16*)(ws + 8388608);
    __bf16* pO = (__bf16*)(ws + 16777216);
    float*  pL = (float*)(ws + 16777216 + 12582912);
    int*  done = (int*)(ws + 16777216 + 12582912 + 196608);

    prep_kernel<<<1024, 256, 0, stream>>>(V, T, Vt, Tb, done);
    fa_kernel<<<512, 256, 0, stream>>>(Q, Tb, Vt, O, pO, pL, done);
}